// Round 6
// baseline (120.155 us; speedup 1.0000x reference)
//
#include <hip/hip_runtime.h>
#include <hip/hip_bf16.h>
#include <hip/hip_cooperative_groups.h>
#include <math.h>

namespace cg = cooperative_groups;

// B=64, C=3, H=W=512.
// out[b,0] = sigmoid( sum_{c,h,w} x[b,c,h,w] * M_col[h,w] / C )
// out[b,1] = sigmoid( sum_{c,h,w} x[b,c,h,w] * M_row[h,w] / C )
// M_row = (1/HW) D^T (diag(rw) A) D ;  M_col = (1/HW) D^T (A diag(cw)) D
// D = orthonormal DCT-II matrix, DT[n][k] = D[k][n].
//
// Structural rules learned (R2-R4):
//  - NO same-address device atomics / fences in the 2048-block streamer
//    (R3/R4: ~100+ us serialized tail).
//  - NO __builtin_nontemporal_load on the x stream (R3: latency-bound crawl).
//  - Streaming kernel needs ~32 waves/CU (R2: 8 waves/CU -> 3x slower).

typedef __attribute__((ext_vector_type(8))) short bf16x8;
typedef __attribute__((ext_vector_type(4))) float f32x4;

#define NFULL 512
#define HWTOT 262144
#define SCALE_M (1.0f / 786432.0f)      // 1/(H*W*C)
#define KC_BLOCKS 2048

static __device__ __forceinline__ unsigned short f_to_bf16(float f) {
  union { float f; unsigned int i; } v; v.f = f;
  unsigned int r = v.i + 0x7FFFu + ((v.i >> 16) & 1u);   // round-nearest-even
  return (unsigned short)(r >> 16);
}

// ---------------- kprep: k0 + ka + kb fused via cooperative grid sync ----------------
// 256 blocks x 256 threads (1 block/CU resident -> cooperative-safe).
// Phase A: DT/Arw/Acw tables.  Phase B: T1=Arw@D, T2=Acw@D (transposed bf16).
// Phase C: Mrow = D^T@T1, Mcol = D^T@T2 (fp32, scaled).
__global__ __launch_bounds__(256, 1) void kprep(
    const float* __restrict__ att, const float* __restrict__ rw,
    const float* __restrict__ cw,
    unsigned short* __restrict__ DT, unsigned short* __restrict__ Arw,
    unsigned short* __restrict__ Acw,
    unsigned short* __restrict__ T1T, unsigned short* __restrict__ T2T,
    float* __restrict__ Mrow, float* __restrict__ Mcol) {
  cg::grid_group grid = cg::this_grid();
  int gtid = blockIdx.x * 256 + threadIdx.x;   // 0..65535

  // ---- Phase A ----
#pragma unroll
  for (int j = 0; j < 4; ++j) {
    int idx = gtid + j * 65536;                // coalesced
    int r = idx >> 9;
    int c = idx & 511;
    unsigned int ph = ((unsigned int)(2 * r + 1) * (unsigned int)c) & 2047u;
    float s = (c == 0) ? 0.04419417382415922f : 0.0625f;
    DT[idx] = f_to_bf16(s * cospif((float)ph * (1.0f / 1024.0f)));
    float a = att[idx];
    Arw[idx] = f_to_bf16(a * rw[r]);
    Acw[idx] = f_to_bf16(a * cw[c]);
  }
  grid.sync();

  // ---- Phase B (ka) ----
  {
    int wave = (blockIdx.x << 2) + (threadIdx.x >> 6);   // 0..1023
    int lane = threadIdx.x & 63;
    int tk = wave >> 5, tw = wave & 31;
    int row_a = tk * 16 + (lane & 15);
    int row_b = tw * 16 + (lane & 15);
    int koff = (lane >> 4) * 8;

    const bf16x8* A1 = (const bf16x8*)(Arw + row_a * NFULL);
    const bf16x8* A2 = (const bf16x8*)(Acw + row_a * NFULL);
    const bf16x8* Bp = (const bf16x8*)(DT  + row_b * NFULL);

    f32x4 acc1 = {0.f, 0.f, 0.f, 0.f};
    f32x4 acc2 = {0.f, 0.f, 0.f, 0.f};
#pragma unroll 4
    for (int l0 = 0; l0 < NFULL; l0 += 32) {
      int e = (l0 + koff) >> 3;
      bf16x8 b = Bp[e];
      acc1 = __builtin_amdgcn_mfma_f32_16x16x32_bf16(A1[e], b, acc1, 0, 0, 0);
      acc2 = __builtin_amdgcn_mfma_f32_16x16x32_bf16(A2[e], b, acc2, 0, 0, 0);
    }
    int col = lane & 15, r0 = (lane >> 4) * 4;
    int w  = tw * 16 + col;
    int k0 = tk * 16 + r0;
    unsigned int g0 = f_to_bf16(acc1[0]) | ((unsigned int)f_to_bf16(acc1[1]) << 16);
    unsigned int g1 = f_to_bf16(acc1[2]) | ((unsigned int)f_to_bf16(acc1[3]) << 16);
    unsigned int c0 = f_to_bf16(acc2[0]) | ((unsigned int)f_to_bf16(acc2[1]) << 16);
    unsigned int c1 = f_to_bf16(acc2[2]) | ((unsigned int)f_to_bf16(acc2[3]) << 16);
    *(uint2*)(T1T + w * NFULL + k0) = make_uint2(g0, g1);
    *(uint2*)(T2T + w * NFULL + k0) = make_uint2(c0, c1);
  }
  grid.sync();

  // ---- Phase C (kb) ----
  {
    int wave = (blockIdx.x << 2) + (threadIdx.x >> 6);
    int lane = threadIdx.x & 63;
    int th = wave >> 5, tw = wave & 31;
    int row_a = th * 16 + (lane & 15);
    int row_b = tw * 16 + (lane & 15);
    int koff = (lane >> 4) * 8;

    const bf16x8* Ap = (const bf16x8*)(DT  + row_a * NFULL);
    const bf16x8* Rp = (const bf16x8*)(T1T + row_b * NFULL);
    const bf16x8* Cp = (const bf16x8*)(T2T + row_b * NFULL);

    f32x4 accR = {0.f, 0.f, 0.f, 0.f};
    f32x4 accC = {0.f, 0.f, 0.f, 0.f};
#pragma unroll 4
    for (int k0 = 0; k0 < NFULL; k0 += 32) {
      int e = (k0 + koff) >> 3;
      bf16x8 a = Ap[e];
      accR = __builtin_amdgcn_mfma_f32_16x16x32_bf16(a, Rp[e], accR, 0, 0, 0);
      accC = __builtin_amdgcn_mfma_f32_16x16x32_bf16(a, Cp[e], accC, 0, 0, 0);
    }
    int col = lane & 15, r0 = (lane >> 4) * 4;
    int h0 = th * 16 + r0;
    int w  = tw * 16 + col;
#pragma unroll
    for (int j = 0; j < 4; ++j) {
      Mrow[(h0 + j) * NFULL + w] = accR[j] * SCALE_M;
      Mcol[(h0 + j) * NFULL + w] = accC[j] * SCALE_M;
    }
  }
}

// ---------------- KC: stream x once; distance-1 software pipeline ----------------
// grid = 64 batches x 32 hw-slices; VGPR target <=64 to keep 32 waves/CU.
// ~10 loads in flight per wave (vs 5 before) to cover HBM latency.
__global__ __launch_bounds__(256) void kc_dot(const float* __restrict__ x,
                                              const float* __restrict__ Mcol,
                                              const float* __restrict__ Mrow,
                                              float* __restrict__ partial) {
  int b   = blockIdx.x >> 5;
  int sub = blockIdx.x & 31;
  int tid = threadIdx.x;
  const f32x4* __restrict__ xb = (const f32x4*)x + (size_t)b * 196608;
  const f32x4* __restrict__ mc = (const f32x4*)Mcol;
  const f32x4* __restrict__ mr = (const f32x4*)Mrow;

  int base = sub * 2048 + tid;

  // prologue loads (iter 0)
  f32x4 m0 = mc[base];
  f32x4 m1 = mr[base];
  f32x4 x0 = xb[base];
  f32x4 x1 = xb[base + 65536];
  f32x4 x2 = xb[base + 131072];

  float a0 = 0.f, a1 = 0.f;
#pragma unroll
  for (int it = 0; it < 8; ++it) {
    f32x4 cm0 = m0, cm1 = m1, cx0 = x0, cx1 = x1, cx2 = x2;
    if (it < 7) {                       // issue next-iter loads before computing
      int i = base + (it + 1) * 256;
      m0 = mc[i];
      m1 = mr[i];
      x0 = xb[i];
      x1 = xb[i + 65536];
      x2 = xb[i + 131072];
    }
    f32x4 sv = cx0 + cx1 + cx2;
    a0 += sv.x * cm0.x + sv.y * cm0.y + sv.z * cm0.z + sv.w * cm0.w;
    a1 += sv.x * cm1.x + sv.y * cm1.y + sv.z * cm1.z + sv.w * cm1.w;
  }

  // wave shuffle reduce, then cross-wave via LDS
  int lane = tid & 63, wv = tid >> 6;
#pragma unroll
  for (int off = 32; off > 0; off >>= 1) {
    a0 += __shfl_down(a0, off);
    a1 += __shfl_down(a1, off);
  }
  __shared__ float red[8];
  if (lane == 0) { red[wv * 2] = a0; red[wv * 2 + 1] = a1; }
  __syncthreads();
  if (tid == 0) {
    float s0 = red[0] + red[2] + red[4] + red[6];
    float s1 = red[1] + red[3] + red[5] + red[7];
    partial[(b * 32 + sub) * 2 + 0] = s0;
    partial[(b * 32 + sub) * 2 + 1] = s1;
  }
}

// ---------------- KD: final deterministic reduce + sigmoid ----------------
__global__ void kd_final(const float* __restrict__ partial, float* __restrict__ out) {
  int t = threadIdx.x;           // 0..127 -> (b, o)
  int b = t >> 1, o = t & 1;
  float s = 0.f;
#pragma unroll
  for (int j = 0; j < 32; ++j) s += partial[(b * 32 + j) * 2 + o];
  out[b * 2 + o] = 1.0f / (1.0f + expf(-s));
}

extern "C" void kernel_launch(void* const* d_in, const int* in_sizes, int n_in,
                              void* d_out, int out_size, void* d_ws, size_t ws_size,
                              hipStream_t stream) {
  const float* x   = (const float*)d_in[0];   // [64,3,512,512]
  const float* att = (const float*)d_in[1];   // [512,512]
  const float* rw  = (const float*)d_in[2];   // [512]
  const float* cw  = (const float*)d_in[3];   // [512]
  float* out = (float*)d_out;                 // [64,2]

  // workspace layout (~4.6 MiB)
  unsigned short* DT  = (unsigned short*)d_ws;        // 512 KB
  unsigned short* Arw = DT  + HWTOT;                  // 512 KB
  unsigned short* Acw = Arw + HWTOT;                  // 512 KB
  unsigned short* T1T = Acw + HWTOT;                  // 512 KB
  unsigned short* T2T = T1T + HWTOT;                  // 512 KB
  float* Mrow    = (float*)(T2T + HWTOT);             // 1 MB
  float* Mcol    = Mrow + HWTOT;                      // 1 MB
  float* partial = Mcol + HWTOT;                      // 16 KB

  void* args[] = {(void*)&att, (void*)&rw, (void*)&cw, (void*)&DT, (void*)&Arw,
                  (void*)&Acw, (void*)&T1T, (void*)&T2T, (void*)&Mrow, (void*)&Mcol};
  hipLaunchCooperativeKernel((void*)kprep, dim3(256), dim3(256), args, 0, stream);
  kc_dot<<<KC_BLOCKS, 256, 0, stream>>>(x, Mcol, Mrow, partial);
  kd_final<<<1, 128, 0, stream>>>(partial, out);
}

// Round 7
// 57.002 us; speedup vs baseline: 2.1079x; 2.1079x over previous
//
#include <hip/hip_runtime.h>
#include <hip/hip_bf16.h>
#include <math.h>

// B=64, C=3, H=W=512.
// out[b,0] = sigmoid( sum_{c,h,w} x[b,c,h,w] * M_col[h,w] / C )
// out[b,1] = sigmoid( sum_{c,h,w} x[b,c,h,w] * M_row[h,w] / C )
// M_row = (1/HW) D^T (diag(rw) A) D ;  M_col = (1/HW) D^T (A diag(cw)) D
// D = orthonormal DCT-II matrix, DT[n][k] = D[k][n].
//
// Structural rules learned (R2-R6):
//  - NO same-address device atomics / fences in the 2048-block streamer
//    (R3/R4: ~100+ us serialized tail).
//  - NO __builtin_nontemporal_load on the x stream (R3: latency-bound crawl).
//  - EVERY phase needs >=16 waves/CU: 8 waves/CU streamer = 3x slower (R2);
//    4 waves/CU cooperative GEMM = +60us (R6). No cooperative fusion at
//    1 block/CU.

typedef __attribute__((ext_vector_type(8))) short bf16x8;
typedef __attribute__((ext_vector_type(4))) float f32x4;

#define NFULL 512
#define HWTOT 262144
#define SCALE_M (1.0f / 786432.0f)      // 1/(H*W*C)
#define KC_BLOCKS 2048

static __device__ __forceinline__ unsigned short f_to_bf16(float f) {
  union { float f; unsigned int i; } v; v.f = f;
  unsigned int r = v.i + 0x7FFFu + ((v.i >> 16) & 1u);   // round-nearest-even
  return (unsigned short)(r >> 16);
}

// ---------------- K0: trig table + scaled bf16 casts ----------------
__global__ void k0_prep(const float* __restrict__ att,
                        const float* __restrict__ rw,
                        const float* __restrict__ cw,
                        unsigned short* __restrict__ DT,
                        unsigned short* __restrict__ Arw,
                        unsigned short* __restrict__ Acw) {
  int idx = blockIdx.x * blockDim.x + threadIdx.x;   // 0..262143
  int r = idx >> 9;
  int c = idx & 511;
  unsigned int ph = ((unsigned int)(2 * r + 1) * (unsigned int)c) & 2047u;  // period 2048
  float s = (c == 0) ? 0.04419417382415922f   // sqrt(1/512)
                     : 0.0625f;               // sqrt(2/512)
  DT[idx] = f_to_bf16(s * cospif((float)ph * (1.0f / 1024.0f)));
  float a = att[idx];
  Arw[idx] = f_to_bf16(a * rw[r]);
  Acw[idx] = f_to_bf16(a * cw[c]);
}

// ---------------- KA: T1 = Arw@D, T2 = Acw@D ; split-K x4, transposed bf16 out ----
// 1024 blocks (one per 16x16 tile) x 4 waves (one per K/4 chunk) -> 16 waves/CU.
// Fixed-order LDS reduce keeps determinism.
__global__ __launch_bounds__(256) void ka_gemm(const unsigned short* __restrict__ DT,
                                               const unsigned short* __restrict__ Arw,
                                               const unsigned short* __restrict__ Acw,
                                               unsigned short* __restrict__ T1T,
                                               unsigned short* __restrict__ T2T) {
  __shared__ f32x4 r1[4][64];
  __shared__ f32x4 r2[4][64];
  int tile = blockIdx.x;               // 0..1023
  int tk = tile >> 5, tw = tile & 31;
  int tid = threadIdx.x, lane = tid & 63, wv = tid >> 6;
  int row_a = tk * 16 + (lane & 15);
  int row_b = tw * 16 + (lane & 15);
  int koff = (lane >> 4) * 8;
  int l0beg = wv * 128;                // this wave's K chunk

  const bf16x8* A1 = (const bf16x8*)(Arw + row_a * NFULL);
  const bf16x8* A2 = (const bf16x8*)(Acw + row_a * NFULL);
  const bf16x8* Bp = (const bf16x8*)(DT  + row_b * NFULL);

  f32x4 acc1 = {0.f, 0.f, 0.f, 0.f};
  f32x4 acc2 = {0.f, 0.f, 0.f, 0.f};
#pragma unroll
  for (int l0 = 0; l0 < 128; l0 += 32) {
    int e = (l0beg + l0 + koff) >> 3;
    bf16x8 b = Bp[e];
    acc1 = __builtin_amdgcn_mfma_f32_16x16x32_bf16(A1[e], b, acc1, 0, 0, 0);
    acc2 = __builtin_amdgcn_mfma_f32_16x16x32_bf16(A2[e], b, acc2, 0, 0, 0);
  }
  r1[wv][lane] = acc1;
  r2[wv][lane] = acc2;
  __syncthreads();
  if (wv == 0) {
    f32x4 s1 = (r1[0][lane] + r1[1][lane]) + (r1[2][lane] + r1[3][lane]);
    f32x4 s2 = (r2[0][lane] + r2[1][lane]) + (r2[2][lane] + r2[3][lane]);
    int col = lane & 15, r0 = (lane >> 4) * 4;
    int w  = tw * 16 + col;
    int k0 = tk * 16 + r0;
    unsigned int g0 = f_to_bf16(s1[0]) | ((unsigned int)f_to_bf16(s1[1]) << 16);
    unsigned int g1 = f_to_bf16(s1[2]) | ((unsigned int)f_to_bf16(s1[3]) << 16);
    unsigned int c0 = f_to_bf16(s2[0]) | ((unsigned int)f_to_bf16(s2[1]) << 16);
    unsigned int c1 = f_to_bf16(s2[2]) | ((unsigned int)f_to_bf16(s2[3]) << 16);
    *(uint2*)(T1T + w * NFULL + k0) = make_uint2(g0, g1);
    *(uint2*)(T2T + w * NFULL + k0) = make_uint2(c0, c1);
  }
}

// ---------------- KB: M_row = D^T @ T1, M_col = D^T @ T2 ; split-K x4, fp32 out ----
__global__ __launch_bounds__(256) void kb_gemm(const unsigned short* __restrict__ DT,
                                               const unsigned short* __restrict__ T1T,
                                               const unsigned short* __restrict__ T2T,
                                               float* __restrict__ Mrow,
                                               float* __restrict__ Mcol) {
  __shared__ f32x4 r1[4][64];
  __shared__ f32x4 r2[4][64];
  int tile = blockIdx.x;
  int th = tile >> 5, tw = tile & 31;
  int tid = threadIdx.x, lane = tid & 63, wv = tid >> 6;
  int row_a = th * 16 + (lane & 15);
  int row_b = tw * 16 + (lane & 15);
  int koff = (lane >> 4) * 8;
  int k0beg = wv * 128;

  const bf16x8* Ap = (const bf16x8*)(DT  + row_a * NFULL);
  const bf16x8* Rp = (const bf16x8*)(T1T + row_b * NFULL);
  const bf16x8* Cp = (const bf16x8*)(T2T + row_b * NFULL);

  f32x4 accR = {0.f, 0.f, 0.f, 0.f};
  f32x4 accC = {0.f, 0.f, 0.f, 0.f};
#pragma unroll
  for (int k0 = 0; k0 < 128; k0 += 32) {
    int e = (k0beg + k0 + koff) >> 3;
    bf16x8 a = Ap[e];
    accR = __builtin_amdgcn_mfma_f32_16x16x32_bf16(a, Rp[e], accR, 0, 0, 0);
    accC = __builtin_amdgcn_mfma_f32_16x16x32_bf16(a, Cp[e], accC, 0, 0, 0);
  }
  r1[wv][lane] = accR;
  r2[wv][lane] = accC;
  __syncthreads();
  if (wv == 0) {
    f32x4 sR = (r1[0][lane] + r1[1][lane]) + (r1[2][lane] + r1[3][lane]);
    f32x4 sC = (r2[0][lane] + r2[1][lane]) + (r2[2][lane] + r2[3][lane]);
    int col = lane & 15, r0 = (lane >> 4) * 4;
    int h0 = th * 16 + r0;
    int w  = tw * 16 + col;
#pragma unroll
    for (int j = 0; j < 4; ++j) {
      Mrow[(h0 + j) * NFULL + w] = sR[j] * SCALE_M;
      Mcol[(h0 + j) * NFULL + w] = sC[j] * SCALE_M;
    }
  }
}

// ---------------- KC: stream x once; distance-1 software pipeline ----------------
// grid = 64 batches x 32 hw-slices -> 32 waves/CU. M (2 MB) rides L2/L3.
__global__ __launch_bounds__(256) void kc_dot(const float* __restrict__ x,
                                              const float* __restrict__ Mcol,
                                              const float* __restrict__ Mrow,
                                              float* __restrict__ partial) {
  int b   = blockIdx.x >> 5;
  int sub = blockIdx.x & 31;
  int tid = threadIdx.x;
  const f32x4* __restrict__ xb = (const f32x4*)x + (size_t)b * 196608;
  const f32x4* __restrict__ mc = (const f32x4*)Mcol;
  const f32x4* __restrict__ mr = (const f32x4*)Mrow;

  int base = sub * 2048 + tid;

  // prologue loads (iter 0)
  f32x4 m0 = mc[base];
  f32x4 m1 = mr[base];
  f32x4 x0 = xb[base];
  f32x4 x1 = xb[base + 65536];
  f32x4 x2 = xb[base + 131072];

  float a0 = 0.f, a1 = 0.f;
#pragma unroll
  for (int it = 0; it < 8; ++it) {
    f32x4 cm0 = m0, cm1 = m1, cx0 = x0, cx1 = x1, cx2 = x2;
    if (it < 7) {                       // issue next-iter loads before computing
      int i = base + (it + 1) * 256;
      m0 = mc[i];
      m1 = mr[i];
      x0 = xb[i];
      x1 = xb[i + 65536];
      x2 = xb[i + 131072];
    }
    f32x4 sv = cx0 + cx1 + cx2;
    a0 += sv.x * cm0.x + sv.y * cm0.y + sv.z * cm0.z + sv.w * cm0.w;
    a1 += sv.x * cm1.x + sv.y * cm1.y + sv.z * cm1.z + sv.w * cm1.w;
  }

  // wave shuffle reduce, then cross-wave via LDS
  int lane = tid & 63, wv = tid >> 6;
#pragma unroll
  for (int off = 32; off > 0; off >>= 1) {
    a0 += __shfl_down(a0, off);
    a1 += __shfl_down(a1, off);
  }
  __shared__ float red[8];
  if (lane == 0) { red[wv * 2] = a0; red[wv * 2 + 1] = a1; }
  __syncthreads();
  if (tid == 0) {
    float s0 = red[0] + red[2] + red[4] + red[6];
    float s1 = red[1] + red[3] + red[5] + red[7];
    partial[(b * 32 + sub) * 2 + 0] = s0;
    partial[(b * 32 + sub) * 2 + 1] = s1;
  }
}

// ---------------- KD: final deterministic reduce + sigmoid ----------------
__global__ void kd_final(const float* __restrict__ partial, float* __restrict__ out) {
  int t = threadIdx.x;           // 0..127 -> (b, o)
  int b = t >> 1, o = t & 1;
  float s = 0.f;
#pragma unroll
  for (int j = 0; j < 32; ++j) s += partial[(b * 32 + j) * 2 + o];
  out[b * 2 + o] = 1.0f / (1.0f + expf(-s));
}

extern "C" void kernel_launch(void* const* d_in, const int* in_sizes, int n_in,
                              void* d_out, int out_size, void* d_ws, size_t ws_size,
                              hipStream_t stream) {
  const float* x   = (const float*)d_in[0];   // [64,3,512,512]
  const float* att = (const float*)d_in[1];   // [512,512]
  const float* rw  = (const float*)d_in[2];   // [512]
  const float* cw  = (const float*)d_in[3];   // [512]
  float* out = (float*)d_out;                 // [64,2]

  // workspace layout (~4.6 MiB)
  unsigned short* DT  = (unsigned short*)d_ws;        // 512 KB
  unsigned short* Arw = DT  + HWTOT;                  // 512 KB
  unsigned short* Acw = Arw + HWTOT;                  // 512 KB
  unsigned short* T1T = Acw + HWTOT;                  // 512 KB
  unsigned short* T2T = T1T + HWTOT;                  // 512 KB
  float* Mrow    = (float*)(T2T + HWTOT);             // 1 MB
  float* Mcol    = Mrow + HWTOT;                      // 1 MB
  float* partial = Mcol + HWTOT;                      // 16 KB

  k0_prep<<<1024, 256, 0, stream>>>(att, rw, cw, DT, Arw, Acw);
  ka_gemm<<<1024, 256, 0, stream>>>(DT, Arw, Acw, T1T, T2T);
  kb_gemm<<<1024, 256, 0, stream>>>(DT, T1T, T2T, Mrow, Mcol);
  kc_dot<<<KC_BLOCKS, 256, 0, stream>>>(x, Mcol, Mrow, partial);
  kd_final<<<1, 128, 0, stream>>>(partial, out);
}

// Round 8
// 56.972 us; speedup vs baseline: 2.1090x; 1.0005x over previous
//
#include <hip/hip_runtime.h>
#include <hip/hip_bf16.h>
#include <math.h>

// B=64, C=3, H=W=512.
// out[b,0] = sigmoid( sum_{c,h,w} x[b,c,h,w] * M_col[h,w] / C )
// out[b,1] = sigmoid( sum_{c,h,w} x[b,c,h,w] * M_row[h,w] / C )
// M_row = (1/HW) D^T (diag(rw) A) D ;  M_col = (1/HW) D^T (A diag(cw)) D
// D = orthonormal DCT-II matrix, DT[n][k] = D[k][n].
//
// Structural rules learned (R2-R7):
//  - NO same-address device atomics / fences in the 2048-block streamer
//    (R3/R4: ~100+ us serialized tail).
//  - NO __builtin_nontemporal_load on the x stream (R3: latency-bound crawl).
//  - EVERY phase needs >=16 waves/CU (R2: 8 waves/CU streamer 3x slower;
//    R6: 4 waves/CU cooperative GEMM +60us). No cooperative fusion at
//    1 block/CU.
//  - kc is issue/depth-limited at ~5 TB/s, not HBM-capped (R7 analysis):
//    cut load slots (bf16-packed M) and deepen the pipeline.

typedef __attribute__((ext_vector_type(8))) short bf16x8;
typedef __attribute__((ext_vector_type(4))) float f32x4;

#define NFULL 512
#define HWTOT 262144
#define SCALE_M (1.0f / 786432.0f)      // 1/(H*W*C)
#define KC_BLOCKS 2048

static __device__ __forceinline__ unsigned short f_to_bf16(float f) {
  union { float f; unsigned int i; } v; v.f = f;
  unsigned int r = v.i + 0x7FFFu + ((v.i >> 16) & 1u);   // round-nearest-even
  return (unsigned short)(r >> 16);
}
static __device__ __forceinline__ float bf_lo(unsigned int u) {
  union { unsigned int i; float f; } v; v.i = u << 16; return v.f;
}
static __device__ __forceinline__ float bf_hi(unsigned int u) {
  union { unsigned int i; float f; } v; v.i = u & 0xFFFF0000u; return v.f;
}

// ---------------- K0: trig table + scaled bf16 casts ----------------
__global__ void k0_prep(const float* __restrict__ att,
                        const float* __restrict__ rw,
                        const float* __restrict__ cw,
                        unsigned short* __restrict__ DT,
                        unsigned short* __restrict__ Arw,
                        unsigned short* __restrict__ Acw) {
  int idx = blockIdx.x * blockDim.x + threadIdx.x;   // 0..262143
  int r = idx >> 9;
  int c = idx & 511;
  unsigned int ph = ((unsigned int)(2 * r + 1) * (unsigned int)c) & 2047u;  // period 2048
  float s = (c == 0) ? 0.04419417382415922f   // sqrt(1/512)
                     : 0.0625f;               // sqrt(2/512)
  DT[idx] = f_to_bf16(s * cospif((float)ph * (1.0f / 1024.0f)));
  float a = att[idx];
  Arw[idx] = f_to_bf16(a * rw[r]);
  Acw[idx] = f_to_bf16(a * cw[c]);
}

// ---------------- KA: T1 = Arw@D, T2 = Acw@D ; split-K x4, transposed bf16 out ----
// 1024 blocks (one per 16x16 tile) x 4 waves -> 16 waves/CU.
__global__ __launch_bounds__(256) void ka_gemm(const unsigned short* __restrict__ DT,
                                               const unsigned short* __restrict__ Arw,
                                               const unsigned short* __restrict__ Acw,
                                               unsigned short* __restrict__ T1T,
                                               unsigned short* __restrict__ T2T) {
  __shared__ f32x4 r1[4][64];
  __shared__ f32x4 r2[4][64];
  int tile = blockIdx.x;               // 0..1023
  int tk = tile >> 5, tw = tile & 31;
  int tid = threadIdx.x, lane = tid & 63, wv = tid >> 6;
  int row_a = tk * 16 + (lane & 15);
  int row_b = tw * 16 + (lane & 15);
  int koff = (lane >> 4) * 8;
  int l0beg = wv * 128;                // this wave's K chunk

  const bf16x8* A1 = (const bf16x8*)(Arw + row_a * NFULL);
  const bf16x8* A2 = (const bf16x8*)(Acw + row_a * NFULL);
  const bf16x8* Bp = (const bf16x8*)(DT  + row_b * NFULL);

  f32x4 acc1 = {0.f, 0.f, 0.f, 0.f};
  f32x4 acc2 = {0.f, 0.f, 0.f, 0.f};
#pragma unroll
  for (int l0 = 0; l0 < 128; l0 += 32) {
    int e = (l0beg + l0 + koff) >> 3;
    bf16x8 b = Bp[e];
    acc1 = __builtin_amdgcn_mfma_f32_16x16x32_bf16(A1[e], b, acc1, 0, 0, 0);
    acc2 = __builtin_amdgcn_mfma_f32_16x16x32_bf16(A2[e], b, acc2, 0, 0, 0);
  }
  r1[wv][lane] = acc1;
  r2[wv][lane] = acc2;
  __syncthreads();
  if (wv == 0) {
    f32x4 s1 = (r1[0][lane] + r1[1][lane]) + (r1[2][lane] + r1[3][lane]);
    f32x4 s2 = (r2[0][lane] + r2[1][lane]) + (r2[2][lane] + r2[3][lane]);
    int col = lane & 15, r0 = (lane >> 4) * 4;
    int w  = tw * 16 + col;
    int k0 = tk * 16 + r0;
    unsigned int g0 = f_to_bf16(s1[0]) | ((unsigned int)f_to_bf16(s1[1]) << 16);
    unsigned int g1 = f_to_bf16(s1[2]) | ((unsigned int)f_to_bf16(s1[3]) << 16);
    unsigned int c0 = f_to_bf16(s2[0]) | ((unsigned int)f_to_bf16(s2[1]) << 16);
    unsigned int c1 = f_to_bf16(s2[2]) | ((unsigned int)f_to_bf16(s2[3]) << 16);
    *(uint2*)(T1T + w * NFULL + k0) = make_uint2(g0, g1);
    *(uint2*)(T2T + w * NFULL + k0) = make_uint2(c0, c1);
  }
}

// ---------------- KB: M = D^T @ T1/T2 ; split-K x4, PACKED bf16 output ----
// Mpk[h*512+w] = bf16(Mcol) | bf16(Mrow)<<16   (one u32 per hw element)
__global__ __launch_bounds__(256) void kb_gemm(const unsigned short* __restrict__ DT,
                                               const unsigned short* __restrict__ T1T,
                                               const unsigned short* __restrict__ T2T,
                                               unsigned int* __restrict__ Mpk) {
  __shared__ f32x4 r1[4][64];
  __shared__ f32x4 r2[4][64];
  int tile = blockIdx.x;
  int th = tile >> 5, tw = tile & 31;
  int tid = threadIdx.x, lane = tid & 63, wv = tid >> 6;
  int row_a = th * 16 + (lane & 15);
  int row_b = tw * 16 + (lane & 15);
  int koff = (lane >> 4) * 8;
  int k0beg = wv * 128;

  const bf16x8* Ap = (const bf16x8*)(DT  + row_a * NFULL);
  const bf16x8* Rp = (const bf16x8*)(T1T + row_b * NFULL);
  const bf16x8* Cp = (const bf16x8*)(T2T + row_b * NFULL);

  f32x4 accR = {0.f, 0.f, 0.f, 0.f};
  f32x4 accC = {0.f, 0.f, 0.f, 0.f};
#pragma unroll
  for (int k0 = 0; k0 < 128; k0 += 32) {
    int e = (k0beg + k0 + koff) >> 3;
    bf16x8 a = Ap[e];
    accR = __builtin_amdgcn_mfma_f32_16x16x32_bf16(a, Rp[e], accR, 0, 0, 0);
    accC = __builtin_amdgcn_mfma_f32_16x16x32_bf16(a, Cp[e], accC, 0, 0, 0);
  }
  r1[wv][lane] = accR;
  r2[wv][lane] = accC;
  __syncthreads();
  if (wv == 0) {
    f32x4 sR = (r1[0][lane] + r1[1][lane]) + (r1[2][lane] + r1[3][lane]);
    f32x4 sC = (r2[0][lane] + r2[1][lane]) + (r2[2][lane] + r2[3][lane]);
    int col = lane & 15, r0 = (lane >> 4) * 4;
    int h0 = th * 16 + r0;
    int w  = tw * 16 + col;
#pragma unroll
    for (int j = 0; j < 4; ++j) {
      Mpk[(h0 + j) * NFULL + w] =
          (unsigned int)f_to_bf16(sC[j] * SCALE_M) |
          ((unsigned int)f_to_bf16(sR[j] * SCALE_M) << 16);
    }
  }
}

// ---------------- KC: stream x once; 4 loads/iter, 3-slot distance-2 pipeline ----
// grid = 64 batches x 32 hw-slices. LB(256,6): ~24 waves/CU, ~12 loads in flight.
__global__ __launch_bounds__(256, 6) void kc_dot(const float* __restrict__ x,
                                                 const unsigned int* __restrict__ Mpk,
                                                 float* __restrict__ partial) {
  int b   = blockIdx.x >> 5;
  int sub = blockIdx.x & 31;
  int tid = threadIdx.x;
  const f32x4* __restrict__ xp = (const f32x4*)x + (size_t)b * 196608;
  const uint4* __restrict__ mp4 = (const uint4*)Mpk;   // 4 hw elems per uint4

  int base = sub * 2048 + tid;

  uint4 mp[3];
  f32x4 xs0[3], xs1[3], xs2[3];
#define LOADIT(s, it)                                   \
  {                                                     \
    int i_ = base + (it) * 256;                         \
    mp[s]  = mp4[i_];                                   \
    xs0[s] = xp[i_];                                    \
    xs1[s] = xp[i_ + 65536];                            \
    xs2[s] = xp[i_ + 131072];                           \
  }
  LOADIT(0, 0)
  LOADIT(1, 1)
  LOADIT(2, 2)

  float a0 = 0.f, a1 = 0.f;
#pragma unroll
  for (int it = 0; it < 8; ++it) {
    int s = it % 3;                    // compile-time after full unroll
    f32x4 sv = (xs0[s] + xs1[s]) + xs2[s];
    uint4 m = mp[s];
    if (it + 3 < 8) LOADIT(s, it + 3)
    a0 += sv.x * bf_lo(m.x) + sv.y * bf_lo(m.y) + sv.z * bf_lo(m.z) + sv.w * bf_lo(m.w);
    a1 += sv.x * bf_hi(m.x) + sv.y * bf_hi(m.y) + sv.z * bf_hi(m.z) + sv.w * bf_hi(m.w);
  }
#undef LOADIT

  // wave shuffle reduce, then cross-wave via LDS
  int lane = tid & 63, wv = tid >> 6;
#pragma unroll
  for (int off = 32; off > 0; off >>= 1) {
    a0 += __shfl_down(a0, off);
    a1 += __shfl_down(a1, off);
  }
  __shared__ float red[8];
  if (lane == 0) { red[wv * 2] = a0; red[wv * 2 + 1] = a1; }
  __syncthreads();
  if (tid == 0) {
    float s0 = red[0] + red[2] + red[4] + red[6];
    float s1 = red[1] + red[3] + red[5] + red[7];
    partial[(b * 32 + sub) * 2 + 0] = s0;
    partial[(b * 32 + sub) * 2 + 1] = s1;
  }
}

// ---------------- KD: final deterministic reduce + sigmoid ----------------
__global__ void kd_final(const float* __restrict__ partial, float* __restrict__ out) {
  int t = threadIdx.x;           // 0..127 -> (b, o)
  int b = t >> 1, o = t & 1;
  float s = 0.f;
#pragma unroll
  for (int j = 0; j < 32; ++j) s += partial[(b * 32 + j) * 2 + o];
  out[b * 2 + o] = 1.0f / (1.0f + expf(-s));
}

extern "C" void kernel_launch(void* const* d_in, const int* in_sizes, int n_in,
                              void* d_out, int out_size, void* d_ws, size_t ws_size,
                              hipStream_t stream) {
  const float* x   = (const float*)d_in[0];   // [64,3,512,512]
  const float* att = (const float*)d_in[1];   // [512,512]
  const float* rw  = (const float*)d_in[2];   // [512]
  const float* cw  = (const float*)d_in[3];   // [512]
  float* out = (float*)d_out;                 // [64,2]

  // workspace layout (~3.6 MiB)
  unsigned short* DT  = (unsigned short*)d_ws;        // 512 KB
  unsigned short* Arw = DT  + HWTOT;                  // 512 KB
  unsigned short* Acw = Arw + HWTOT;                  // 512 KB
  unsigned short* T1T = Acw + HWTOT;                  // 512 KB
  unsigned short* T2T = T1T + HWTOT;                  // 512 KB
  unsigned int*  Mpk  = (unsigned int*)(T2T + HWTOT); // 1 MB
  float* partial = (float*)(Mpk + HWTOT);             // 16 KB

  k0_prep<<<1024, 256, 0, stream>>>(att, rw, cw, DT, Arw, Acw);
  ka_gemm<<<1024, 256, 0, stream>>>(DT, Arw, Acw, T1T, T2T);
  kb_gemm<<<1024, 256, 0, stream>>>(DT, T1T, T2T, Mpk);
  kc_dot<<<KC_BLOCKS, 256, 0, stream>>>(x, Mpk, partial);
  kd_final<<<1, 128, 0, stream>>>(partial, out);
}